// Round 9
// baseline (48.094 us; speedup 1.0000x reference)
//
#include <hip/hip_runtime.h>
#include <stdint.h>

#define N_   64
#define C_   64
#define W_   4096
#define F_   64
#define WW_  9
#define OW_  4088        // W_ - WW_ + 1
#define WBLK 128
#define WROWS 136        // WBLK + 8 halo

typedef __bf16 bf16x8 __attribute__((ext_vector_type(8)));
typedef float  f32x4  __attribute__((ext_vector_type(4)));

__device__ __forceinline__ unsigned short f2bf(float f) {
    union { float f; uint32_t u; } v; v.f = f;
    uint32_t u = v.u;
    return (unsigned short)((u + 0x7FFFu + ((u >> 16) & 1u)) >> 16);  // RNE
}

// pack 4 floats -> 4 bf16 (two v_cvt_pk_bf16_f32, RNE); low half = first operand
__device__ __forceinline__ uint2 pk4(float a, float b, float c, float d) {
    uint2 r;
    asm volatile("v_cvt_pk_bf16_f32 %0, %1, %2" : "=v"(r.x) : "v"(a), "v"(b));
    asm volatile("v_cvt_pk_bf16_f32 %0, %1, %2" : "=v"(r.y) : "v"(c), "v"(d));
    return r;
}

// filt fp32 [F][C][WW] -> filtB bf16, fragment-major [t][f0h][m][u][lane][8j]
//   f = f0h*32 + u*16 + (lane&15),  c = m*32 + (lane>>4)*8 + j
// Each B-fragment load in the main kernel is ONE contiguous 1KB wave load (L2-resident).
__global__ __launch_bounds__(256) void prep_filt_k(const float* __restrict__ filt,
                                                   unsigned short* __restrict__ filtB) {
    int id = blockIdx.x * 256 + threadIdx.x;
    if (id < WW_ * F_ * C_) {
        int j    = id & 7;
        int lane = (id >> 3) & 63;
        int u    = (id >> 9) & 1;
        int m    = (id >> 10) & 1;
        int f0h  = (id >> 11) & 1;
        int t    = id >> 12;
        int l15  = lane & 15, lg = lane >> 4;
        int f = f0h * 32 + u * 16 + l15;
        int c = m * 32 + lg * 8 + j;
        filtB[id] = f2bf(filt[(f * C_ + c) * WW_ + t]);
    }
}

// Block = 256 thr = 4 waves, handles TWO 128-w tiles of one n (double-buffered LDS).
// Async-stage pipeline: tile k+1's global loads are issued BEFORE tile k's compute,
// held in ~36 regs across it (cap 128 via (256,4) -> no spill, unlike round 3's 85).
__global__ __launch_bounds__(256, 4) void conv_k(const float* __restrict__ x,
                                                 const unsigned short* __restrict__ filtB,
                                                 const float* __restrict__ bias,
                                                 float* __restrict__ out) {
    __shared__ unsigned short xs[2][WROWS * 64];   // 2 x 17408 B, swizzled 128B rows

    const int tid   = threadIdx.x;
    const int lane  = tid & 63;
    const int wv    = tid >> 6;
    const int n     = blockIdx.y;
    const int wbase = blockIdx.x * (2 * WBLK);

    // ---- stage maps (R4's proven transpose map, split into LOADS / WRITE) ----
    const int c4 = (wv << 4) + (((tid >> 4) & 3) << 2);   // 4 consecutive c rows
    const int wq = (tid & 15) << 2;                       // w-quad 0..60
    const int cg = c4 >> 3;
    const int cs = c4 & 7;
    const float* xb = x + ((size_t)(n * C_ + c4)) * W_;
    // halo: threads 0..127, one float4 each: c = tid>>1, w-quad 128 + (tid&1)*4
    const int hcw = tid >> 1;
    const int hwq = 128 + ((tid & 1) << 2);
    const int hcg = hcw >> 3;
    const int hcs = hcw & 7;
    const float* hb = x + ((size_t)(n * C_ + hcw)) * W_;

    float4 r[2][4];
    float4 rh;

    auto LOADS = [&](int w0) {
        #pragma unroll
        for (int j = 0; j < 2; ++j)
            #pragma unroll
            for (int k = 0; k < 4; ++k)
                r[j][k] = *reinterpret_cast<const float4*>(xb + (size_t)k * W_ + w0 + wq + j * 64);
        if (tid < 128) {
            int gw = w0 + hwq;                 // quad-aligned; W_%4==0 -> whole-quad guard
            if (gw < W_) rh = *reinterpret_cast<const float4*>(hb + gw);
            else         rh = (float4){0.f, 0.f, 0.f, 0.f};
        }
    };

    auto WRITE = [&](int b) {
        unsigned short* dst = xs[b];
        #pragma unroll
        for (int j = 0; j < 2; ++j) {
            #pragma unroll
            for (int jj = 0; jj < 4; ++jj) {
                int w = wq + j * 64 + jj;
                uint2 u2 = pk4((&r[j][0].x)[jj], (&r[j][1].x)[jj],
                               (&r[j][2].x)[jj], (&r[j][3].x)[jj]);
                *reinterpret_cast<uint2*>(&dst[w * 64 + ((cg ^ (w & 7)) << 3) + cs]) = u2;
            }
        }
        if (tid < 128) {                       // halo: 4 scalar u16 writes (one-off, cheap)
            #pragma unroll
            for (int jj = 0; jj < 4; ++jj) {
                int w = hwq + jj;
                dst[w * 64 + ((hcg ^ (w & 7)) << 3) + hcs] = f2bf((&rh.x)[jj]);
            }
        }
    };

    // ---- compute geometry: wave quadrant = 64w x 32f ----
    const int f0h = wv & 1;
    const int whb = (wv >> 1) * 64;
    const int l15 = lane & 15;
    const int lg  = lane >> 4;
    const unsigned short* Bb = filtB + f0h * 2048 + lane * 8;
    const float bv0 = 64.0f * bias[f0h * 32 + l15];        // ref adds bias per channel -> C*bias
    const float bv1 = 64.0f * bias[f0h * 32 + 16 + l15];

    auto COMPUTE = [&](int b, int w0) {
        const unsigned short* src = xs[b];
        f32x4 acc[4][2];
        #pragma unroll
        for (int s = 0; s < 4; ++s) {
            acc[s][0] = (f32x4){0.f, 0.f, 0.f, 0.f};
            acc[s][1] = (f32x4){0.f, 0.f, 0.f, 0.f};
        }
        #pragma unroll
        for (int t = 0; t < WW_; ++t) {
            #pragma unroll
            for (int m = 0; m < 2; ++m) {
                bf16x8 b0 = *reinterpret_cast<const bf16x8*>(Bb + t * 4096 + m * 1024);
                bf16x8 b1 = *reinterpret_cast<const bf16x8*>(Bb + t * 4096 + m * 1024 + 512);
                #pragma unroll
                for (int s = 0; s < 4; ++s) {
                    int row   = whb + s * 16 + l15 + t;              // <= 135
                    int chunk = ((m << 2) | lg) ^ (row & 7);
                    bf16x8 a  = *reinterpret_cast<const bf16x8*>(&src[row * 64 + chunk * 8]);
                    acc[s][0] = __builtin_amdgcn_mfma_f32_16x16x32_bf16(a, b0, acc[s][0], 0, 0, 0);
                    acc[s][1] = __builtin_amdgcn_mfma_f32_16x16x32_bf16(a, b1, acc[s][1], 0, 0, 0);
                }
            }
        }
        const int fb = f0h * 32 + l15;
        #pragma unroll
        for (int s = 0; s < 4; ++s) {
            int wg = w0 + whb + s * 16 + lg * 4;
            if (wg < OW_) {                    // wg%4==0, OW_%4==0 -> whole float4 in-range
                float4 o0, o1;
                o0.x = acc[s][0][0] + bv0; o0.y = acc[s][0][1] + bv0;
                o0.z = acc[s][0][2] + bv0; o0.w = acc[s][0][3] + bv0;
                o1.x = acc[s][1][0] + bv1; o1.y = acc[s][1][1] + bv1;
                o1.z = acc[s][1][2] + bv1; o1.w = acc[s][1][3] + bv1;
                *reinterpret_cast<float4*>(out + ((size_t)(n * F_ + fb) * OW_ + wg))      = o0;
                *reinterpret_cast<float4*>(out + ((size_t)(n * F_ + fb + 16) * OW_ + wg)) = o1;
            }
        }
    };

    // ---- 2-tile async pipeline ----
    LOADS(wbase);                 // tile-0 global loads
    WRITE(0);                     // convert + swizzled LDS write (waits tile-0 loads)
    LOADS(wbase + WBLK);          // tile-1 loads issued EARLY: in flight across compute
    __syncthreads();
    COMPUTE(0, wbase);            // MFMA + stores for tile 0 (hides tile-1 HBM latency)
    WRITE(1);                     // tile-1 data arrived; write buf 1
    __syncthreads();
    COMPUTE(1, wbase + WBLK);     // tile 1
}

extern "C" void kernel_launch(void* const* d_in, const int* in_sizes, int n_in,
                              void* d_out, int out_size, void* d_ws, size_t ws_size,
                              hipStream_t stream) {
    const float* x    = (const float*)d_in[0];
    const float* filt = (const float*)d_in[1];
    const float* bias = (const float*)d_in[2];
    float* out        = (float*)d_out;

    unsigned short* filtB = (unsigned short*)d_ws;   // 9*64*64 bf16 = 73728 B

    prep_filt_k<<<(WW_ * F_ * C_ + 255) / 256, 256, 0, stream>>>(filt, filtB);

    dim3 grid(W_ / (2 * WBLK), N_);   // 16 x 64 = 1024 blocks (2 tiles each), 4/CU
    conv_k<<<grid, 256, 0, stream>>>(x, filtB, bias, out);
}